// Round 4
// baseline (21595.714 us; speedup 1.0000x reference)
//
#include <hip/hip_runtime.h>
#include <math.h>

// Problem constants (match reference)
#define Hn   2560      // hidden units
#define Bn   64        // batch
#define INW  128       // input width
#define ETOT 2048      // total excitatory units (4 areas x 512)

__device__ __forceinline__ int area_of(int h) {
  return h < ETOT ? (h >> 9) : ((h - ETOT) >> 7);
}

// ---------------------------------------------------------------------------
// Prep 1: WT[k][h] = sign(k) * |Wrec[h][k]| * conn(h,k), diag removed.
// ---------------------------------------------------------------------------
__global__ void build_wrecT(const float* __restrict__ Wrec, float* __restrict__ WT) {
  __shared__ float tile[64][65];
  int h0 = blockIdx.x * 64;
  int k0 = blockIdx.y * 64;
  int tx = threadIdx.x;   // 0..63
  int ty = threadIdx.y;   // 0..15
  #pragma unroll
  for (int j = 0; j < 64; j += 16)
    tile[ty + j][tx] = Wrec[(size_t)(h0 + ty + j) * Hn + k0 + tx];
  __syncthreads();
  #pragma unroll
  for (int j = 0; j < 64; j += 16) {
    int k = k0 + ty + j;   // out row (source unit)
    int h = h0 + tx;       // out col (target unit), lane-minor -> coalesced
    float v = fabsf(tile[tx][ty + j]);
    int ah = area_of(h);
    int conn;
    float sgn;
    if (k < ETOT) { int ak = k >> 9; int d = ah - ak; conn = (d <= 1 && d >= -1); sgn = 1.f; }
    else          { int ak = (k - ETOT) >> 7; conn = (ah == ak); sgn = -1.f; }
    if (h == k) conn = 0;
    WT[(size_t)k * Hn + h] = conn ? sgn * v : 0.f;
  }
}

// ---------------------------------------------------------------------------
// Prep 2: WinT[i][h] = |Win[h][i]| * (area(h)==0). Row stride Hn (same as WT).
// ---------------------------------------------------------------------------
__global__ void build_winT(const float* __restrict__ Win, float* __restrict__ WinT) {
  __shared__ float tile[64][65];
  int h0 = blockIdx.x * 64;
  int i0 = blockIdx.y * 64;
  int tx = threadIdx.x, ty = threadIdx.y;
  #pragma unroll
  for (int j = 0; j < 64; j += 16)
    tile[ty + j][tx] = Win[(size_t)(h0 + ty + j) * INW + i0 + tx];
  __syncthreads();
  #pragma unroll
  for (int j = 0; j < 64; j += 16) {
    int i = i0 + ty + j;
    int h = h0 + tx;
    float v = fabsf(tile[tx][ty + j]);
    WinT[(size_t)i * Hn + h] = (area_of(h) == 0) ? v : 0.f;
  }
}

// ---------------------------------------------------------------------------
// Prep 3: inpT[t][i][b] = inputs[t][b][i].
// ---------------------------------------------------------------------------
__global__ void build_inpT(const float* __restrict__ inp, float* __restrict__ inpT) {
  __shared__ float tile[64 * 129];
  int t = blockIdx.x;
  const float* src = inp + (size_t)t * Bn * INW;
  float* dst = inpT + (size_t)t * INW * Bn;
  for (int idx = threadIdx.x; idx < Bn * INW; idx += blockDim.x) {
    int b = idx >> 7, i = idx & 127;
    tile[b * 129 + i] = src[idx];
  }
  __syncthreads();
  for (int idx = threadIdx.x; idx < Bn * INW; idx += blockDim.x) {
    int i = idx >> 6, b = idx & 63;
    dst[idx] = tile[b * 129 + i];
  }
}

// ---------------------------------------------------------------------------
// Kernel A (per step): masked GEMM. 3600 chunk-waves (16 h x 64 b x 64 k),
// packed 4 waves/block -> 900 blocks = 3.5 blocks/CU = 14 waves/CU
// (3.5 waves/SIMD: enough co-resident VALU work to hide L2/L3 load latency).
// Results accumulated into pre[h][b] with fp32 global atomics (device-
// coherent, ~22 adds per address per step -> negligible contention).
// ---------------------------------------------------------------------------
__global__ __launch_bounds__(256) void rnn_mm(
    const float* __restrict__ WT, const float* __restrict__ WinT,
    const float* __restrict__ inpT, const float* __restrict__ inp,
    const float* __restrict__ rsrc, float* __restrict__ pre,
    int t, int useInpT)
{
  int g = blockIdx.x * 4 + (threadIdx.x >> 6);   // global chunk id, 0..3599
  int lane = threadIdx.x & 63;

  // g -> (h-group of 16, chunk id). Chunks are 64 k.
  // Per hg: 2*nE E-chunks + 2 I-chunks (+ 2 input chunks for area 0).
  int hg, c;
  if (g < 640)       { hg = g / 20;                c = g % 20; }
  else if (g < 2304) { int r = g - 640;  hg = 32 + r / 26;  c = r % 26; }
  else if (g < 2880) { int r = g - 2304; hg = 96 + r / 18;  c = r % 18; }
  else if (g < 3040) { int r = g - 2880; hg = 128 + r / 20; c = r % 20; }
  else if (g < 3456) { int r = g - 3040; hg = 136 + r / 26; c = r % 26; }
  else               { int r = g - 3456; hg = 152 + r / 18; c = r % 18; }

  int h0 = hg * 16;
  int a  = (hg < 128) ? (hg >> 5) : ((hg - 128) >> 3);
  int nE2 = (a == 0 || a == 3) ? 16 : 24;        // 64-k E chunks
  int kE0 = (a == 0 ? 0 : (a - 1)) * 512;

  const float* wp;          // 16 consecutive floats per k-row, row stride Hn
  const float* rp;          // [64][64] operand rows, stride 64
  bool rawInput = false;
  if (c < nE2) {
    int k0 = kE0 + (c << 6);
    wp = WT + (size_t)k0 * Hn + h0; rp = rsrc + ((size_t)k0 << 6);
  } else if (c < nE2 + 2) {
    int k0 = ETOT + (a << 7) + ((c - nE2) << 6);
    wp = WT + (size_t)k0 * Hn + h0; rp = rsrc + ((size_t)k0 << 6);
  } else {                  // input-projection chunk (area 0 only)
    int i0 = (c - nE2 - 2) << 6;
    wp = WinT + (size_t)i0 * Hn + h0;
    if (useInpT) rp = inpT + (size_t)t * (INW * Bn) + ((size_t)i0 << 6);
    else { rp = inp + (size_t)t * (Bn * INW) + i0; rawInput = true; }
  }

  float acc[16];
  #pragma unroll
  for (int i = 0; i < 16; ++i) acc[i] = 0.f;

  if (!rawInput) {
    #pragma unroll 4
    for (int k = 0; k < 64; ++k) {
      const float4* wq = (const float4*)(wp + (size_t)k * Hn);  // wave-uniform
      float4 w0 = wq[0], w1 = wq[1], w2 = wq[2], w3 = wq[3];
      float rv = rp[(k << 6) + lane];                           // coalesced
      acc[ 0] = fmaf(w0.x, rv, acc[ 0]);  acc[ 1] = fmaf(w0.y, rv, acc[ 1]);
      acc[ 2] = fmaf(w0.z, rv, acc[ 2]);  acc[ 3] = fmaf(w0.w, rv, acc[ 3]);
      acc[ 4] = fmaf(w1.x, rv, acc[ 4]);  acc[ 5] = fmaf(w1.y, rv, acc[ 5]);
      acc[ 6] = fmaf(w1.z, rv, acc[ 6]);  acc[ 7] = fmaf(w1.w, rv, acc[ 7]);
      acc[ 8] = fmaf(w2.x, rv, acc[ 8]);  acc[ 9] = fmaf(w2.y, rv, acc[ 9]);
      acc[10] = fmaf(w2.z, rv, acc[10]);  acc[11] = fmaf(w2.w, rv, acc[11]);
      acc[12] = fmaf(w3.x, rv, acc[12]);  acc[13] = fmaf(w3.y, rv, acc[13]);
      acc[14] = fmaf(w3.z, rv, acc[14]);  acc[15] = fmaf(w3.w, rv, acc[15]);
    }
  } else {
    #pragma unroll 4
    for (int k = 0; k < 64; ++k) {
      const float4* wq = (const float4*)(wp + (size_t)k * Hn);
      float4 w0 = wq[0], w1 = wq[1], w2 = wq[2], w3 = wq[3];
      float rv = rp[lane * INW + k];
      acc[ 0] = fmaf(w0.x, rv, acc[ 0]);  acc[ 1] = fmaf(w0.y, rv, acc[ 1]);
      acc[ 2] = fmaf(w0.z, rv, acc[ 2]);  acc[ 3] = fmaf(w0.w, rv, acc[ 3]);
      acc[ 4] = fmaf(w1.x, rv, acc[ 4]);  acc[ 5] = fmaf(w1.y, rv, acc[ 5]);
      acc[ 6] = fmaf(w1.z, rv, acc[ 6]);  acc[ 7] = fmaf(w1.w, rv, acc[ 7]);
      acc[ 8] = fmaf(w2.x, rv, acc[ 8]);  acc[ 9] = fmaf(w2.y, rv, acc[ 9]);
      acc[10] = fmaf(w2.z, rv, acc[10]);  acc[11] = fmaf(w2.w, rv, acc[11]);
      acc[12] = fmaf(w3.x, rv, acc[12]);  acc[13] = fmaf(w3.y, rv, acc[13]);
      acc[14] = fmaf(w3.z, rv, acc[14]);  acc[15] = fmaf(w3.w, rv, acc[15]);
    }
  }

  // accumulate into pre[h][b] (16 coalesced 256 B atomic adds)
  float* pb = pre + (size_t)h0 * 64 + lane;
  #pragma unroll
  for (int h = 0; h < 16; ++h) atomicAdd(pb + h * 64, acc[h]);
}

// ---------------------------------------------------------------------------
// Kernel B (per step): epilogue. pre -> leaky-integrate -> retanh -> stores;
// re-zeros pre for the next step. 320 blocks x 256 threads (8 h x 64 b each).
// rates written line-packed ([b][h] float4 segments) via padded LDS tile.
// ---------------------------------------------------------------------------
__global__ __launch_bounds__(256) void rnn_fin(
    float* __restrict__ pre, const float* __restrict__ brec,
    float* __restrict__ xT, float* __restrict__ rdst,
    float* __restrict__ rates, int t)
{
  __shared__ float lds[8][65];
  int h0 = blockIdx.x * 8;
  int b  = threadIdx.x & 63;
  int hl = threadIdx.x >> 6;      // 0..3

  #pragma unroll
  for (int j = 0; j < 2; ++j) {
    int h = hl + j * 4;           // local h 0..7
    size_t idx = (size_t)(h0 + h) * 64 + b;
    float p = pre[idx];
    pre[idx] = 0.f;               // reset for next step's atomics
    float x = xT[idx];
    x = 0.8f * x + 0.2f * (p + brec[h0 + h]);   // ALPHA_X = 0.2
    xT[idx] = x;
    float rr = tanhf(fmaxf(x, 0.f));
    rdst[idx] = rr;
    lds[h][b] = rr;
  }
  __syncthreads();

  // rates[t][b][h]: 64 b-rows x 8 h = two float4 segments per row
  if (threadIdx.x < 128) {
    int bb = threadIdx.x >> 1, q = threadIdx.x & 1;
    float4 v = make_float4(lds[q * 4 + 0][bb], lds[q * 4 + 1][bb],
                           lds[q * 4 + 2][bb], lds[q * 4 + 3][bb]);
    *(float4*)(rates + (size_t)t * (Bn * Hn) + (size_t)bb * Hn + h0 + q * 4) = v;
  }
}

// ---------------------------------------------------------------------------
extern "C" void kernel_launch(void* const* d_in, const int* in_sizes, int n_in,
                              void* d_out, int out_size, void* d_ws, size_t ws_size,
                              hipStream_t stream) {
  const float* inputs = (const float*)d_in[0];   // [T, 64, 128]
  const float* Wrec   = (const float*)d_in[1];   // [2560, 2560]
  const float* brec   = (const float*)d_in[2];   // [2560]
  const float* Win    = (const float*)d_in[3];   // [2560, 128]
  int T = in_sizes[0] / (Bn * INW);              // 500

  float* ws = (float*)d_ws;
  size_t off = 0;
  float* WT   = ws + off; off += (size_t)Hn * Hn;          // 26.2 MB
  float* WinT = ws + off; off += (size_t)INW * Hn;         // 1.3 MB
  float* xT   = ws + off; off += (size_t)Hn * Bn;
  float* rA   = ws + off; off += (size_t)Hn * Bn;
  float* rB   = ws + off; off += (size_t)Hn * Bn;
  float* pre  = ws + off; off += (size_t)Hn * Bn;          // 0.64 MB
  float* inpT = ws + off;
  size_t needInpT = (off + (size_t)T * INW * Bn) * sizeof(float);
  int useInpT = (ws_size >= needInpT) ? 1 : 0;

  // x0 = 0, r0 = retanh(0) = 0, pre = 0  (ws poisoned 0xAA each call)
  hipMemsetAsync(xT,  0, (size_t)Hn * Bn * sizeof(float), stream);
  hipMemsetAsync(rA,  0, (size_t)Hn * Bn * sizeof(float), stream);
  hipMemsetAsync(pre, 0, (size_t)Hn * Bn * sizeof(float), stream);

  build_wrecT<<<dim3(40, 40), dim3(64, 16), 0, stream>>>(Wrec, WT);
  build_winT<<<dim3(40, 2), dim3(64, 16), 0, stream>>>(Win, WinT);
  if (useInpT) build_inpT<<<T, 256, 0, stream>>>(inputs, inpT);

  float* rates = (float*)d_out;
  for (int t = 0; t < T; ++t) {
    const float* rs = (t & 1) ? rB : rA;
    float*       rd = (t & 1) ? rA : rB;
    rnn_mm<<<900, 256, 0, stream>>>(WT, WinT, inpT, inputs, rs, pre, t, useInpT);
    rnn_fin<<<320, 256, 0, stream>>>(pre, brec, xT, rd, rates, t);
  }
}